// Round 4
// baseline (80.852 us; speedup 1.0000x reference)
//
#include <hip/hip_runtime.h>
#include <math.h>

// Problem constants (reference is fixed-shape).
#define B_ 16
#define N_ 2048
#define D_ 128

typedef __attribute__((ext_vector_type(8))) short bf16x8;   // 8 bf16 = 4 VGPRs
typedef __attribute__((ext_vector_type(4))) float f32x4;

__device__ __forceinline__ unsigned short f2bf(float f) {
    unsigned u = __float_as_uint(f);
    u += 0x7FFFu + ((u >> 16) & 1u);
    return (unsigned short)(u >> 16);
}

__device__ __forceinline__ unsigned minkey(float f) {
    // order-preserving uint encoding of float (for atomicMin): exact, assoc.
    unsigned u = __float_as_uint(f);
    return u ^ ((unsigned)((int)u >> 31) | 0x80000000u);
}

// ---------------------------------------------------------------------------
// K1: fp32 -> bf16 (pre-swizzled) + fp32 squared norms + per-call re-init of
// pmk keys and the finalize counter (harness does not re-poison between
// replays; ALL state must be rebuilt every call).
// Swizzle: element d of row r stored at d ^ ((r&7)<<3): a linear global->LDS
// copy then gives conflict-free ds_read_b128 when read with the same XOR.
// ---------------------------------------------------------------------------
__global__ __launch_bounds__(256) void prep_kernel(
        const float* __restrict__ X, unsigned short* __restrict__ Xs,
        float* __restrict__ sqn, unsigned* __restrict__ pmk,
        unsigned* __restrict__ fincnt) {
    int row = blockIdx.x * 4 + (threadIdx.x >> 6);
    int ln  = threadIdx.x & 63;
    const float* src = X + (size_t)row * D_;
    float2 v = *(const float2*)(src + ln * 2);
    unsigned short h0 = f2bf(v.x), h1 = f2bf(v.y);
    float f0 = __uint_as_float((unsigned)h0 << 16);
    float f1 = __uint_as_float((unsigned)h1 << 16);
    float s = f0 * f0 + f1 * f1;
    #pragma unroll
    for (int o = 32; o; o >>= 1) s += __shfl_xor(s, o, 64);
    int dsw = (ln * 2) ^ ((row & 7) << 3);
    *(unsigned*)(Xs + (size_t)row * D_ + dsw) =
        (unsigned)h0 | ((unsigned)h1 << 16);
    if (ln == 0) { sqn[row] = s; pmk[row] = 0xFFFFFFFFu; }
    if (blockIdx.x == 0 && threadIdx.x == 0) *fincnt = 0u;
}

// ---------------------------------------------------------------------------
// K2: symmetric fused Gram + min + (last-WG) finalize.
// 576 WGs = 16 batches x 36 upper-triangle pairs of 256-row tiles (it<=jt).
// WG = 256 thr = 4 waves; wave owns 64 i-rows (M=64 -> 256 B LDS-read/MFMA,
// under the LDS ceiling).  acc is quartered (nh=4 passes of 64 cols) to keep
// VGPR <= 256 so TWO WGs co-reside per CU (LDS 68 KB).  j-tile staged once
// into LDS via linear global_load_lds of the pre-swizzled layout.
// Off-diagonal blocks fold BOTH row-mins (pmk[i]) and col-mins (pmk[j]);
// diagonal blocks mask i==j by index.  uint-keyed atomicMin = exact float
// min, order-independent -> deterministic.  The 576th-arriving WG (device
// counter) computes mean/std/CV from pmk+sqn via agent-scope loads.
// ---------------------------------------------------------------------------
__global__ __launch_bounds__(256, 2) void nnd_kernel(
        const unsigned short* __restrict__ Xs, const float* __restrict__ sqn,
        unsigned* __restrict__ pmk, unsigned* __restrict__ fincnt,
        float* __restrict__ out) {
    __shared__ unsigned short Xj[256 * D_];   // 64 KB j-block
    __shared__ float cs[4][256];              // 4 KB col-min cross-wave scratch
    __shared__ double fa1[4], fa2[4];
    __shared__ int lastflag;

    // XCD-chunked remap (576 = 8 x 72, bijective).
    int wg = (int)blockIdx.x;
    int id = (wg & 7) * 72 + (wg >> 3);
    int b  = id / 36;
    int p  = id % 36;
    int it = 0;
    { int q = p; while (q >= 8 - it) { q -= 8 - it; ++it; } p = q; }
    int jt = it + p;
    bool diag = (it == jt);

    int tid = threadIdx.x, wv = tid >> 6, ln = tid & 63;
    int lr = ln & 15;                 // fragment row/col lane index
    int kg = (ln >> 4) * 8;           // A/B fragment k-group offset
    int rg = (ln >> 4) * 4;           // C/D fragment row-group offset

    const unsigned short* Xb  = Xs  + (size_t)b * N_ * D_;
    const float*          sqb = sqn + b * N_;
    int ibase = it * 256, jbase = jt * 256;

    // Stage j-block: 64 KB linear copy, 4 waves x 16 x (64 lanes x 16 B).
    {
        const char* g = (const char*)(Xb + (size_t)jbase * D_) + wv * 16384 + ln * 16;
        char*       l = (char*)Xj + wv * 16384;
        #pragma unroll
        for (int i = 0; i < 16; ++i)
            __builtin_amdgcn_global_load_lds(
                (const __attribute__((address_space(1))) unsigned int*)(g + i * 1024),
                (__attribute__((address_space(3))) unsigned int*)(l + i * 1024),
                16, 0, 0);
    }

    // A fragments: this wave's 64 i-rows x K=128, registers for whole block.
    bf16x8 Af[4][4];
    #pragma unroll
    for (int m = 0; m < 4; ++m) {
        int r  = ibase + wv * 64 + m * 16 + lr;
        const unsigned short* rp = Xb + (size_t)r * D_;
        int sw = (r & 7) << 3;
        #pragma unroll
        for (int ks = 0; ks < 4; ++ks)
            Af[m][ks] = *(const bf16x8*)(rp + ((ks * 32 + kg) ^ sw));
    }

    float ni[4][4];
    #pragma unroll
    for (int m = 0; m < 4; ++m)
        #pragma unroll
        for (int rr = 0; rr < 4; ++rr)
            ni[m][rr] = sqb[ibase + wv * 64 + m * 16 + rg + rr];

    float rmin[16];
    #pragma unroll
    for (int q = 0; q < 16; ++q) rmin[q] = 1e30f;
    const f32x4 zero4 = {0.f, 0.f, 0.f, 0.f};

    __syncthreads();   // staging complete (compiler drains vmcnt before barrier)

    #pragma unroll
    for (int nh = 0; nh < 4; ++nh) {          // 64-col quarters
        float nj[4];
        #pragma unroll
        for (int n = 0; n < 4; ++n)
            nj[n] = sqb[jbase + nh * 64 + n * 16 + lr];

        f32x4 acc[4][4];
        #pragma unroll
        for (int ks = 0; ks < 4; ++ks) {
            bf16x8 Bf[4];
            #pragma unroll
            for (int n = 0; n < 4; ++n) {
                int c = nh * 64 + n * 16 + lr;
                Bf[n] = *(const bf16x8*)(&Xj[c * D_ +
                                             ((ks * 32 + kg) ^ ((c & 7) << 3))]);
            }
            #pragma unroll
            for (int m = 0; m < 4; ++m)
                #pragma unroll
                for (int n = 0; n < 4; ++n)
                    acc[m][n] = __builtin_amdgcn_mfma_f32_16x16x32_bf16(
                        Af[m][ks], Bf[n], ks ? acc[m][n] : zero4, 0, 0, 0);
        }

        // Epilogue.  C/D layout: col = lane&15, row = rg + reg  [m89/m91].
        if (!diag) {
            float cmin[4] = {1e30f, 1e30f, 1e30f, 1e30f};
            #pragma unroll
            for (int m = 0; m < 4; ++m)
                #pragma unroll
                for (int rr = 0; rr < 4; ++rr) {
                    float t0 = fmaf(-2.f, acc[m][0][rr], nj[0]);
                    float t1 = fmaf(-2.f, acc[m][1][rr], nj[1]);
                    float t2 = fmaf(-2.f, acc[m][2][rr], nj[2]);
                    float t3 = fmaf(-2.f, acc[m][3][rr], nj[3]);
                    rmin[m * 4 + rr] = fminf(rmin[m * 4 + rr],
                                             fminf(fminf(t0, t1), fminf(t2, t3)));
                    float nim = ni[m][rr];
                    cmin[0] = fminf(cmin[0], fmaf(-2.f, acc[m][0][rr], nim));
                    cmin[1] = fminf(cmin[1], fmaf(-2.f, acc[m][1][rr], nim));
                    cmin[2] = fminf(cmin[2], fmaf(-2.f, acc[m][2][rr], nim));
                    cmin[3] = fminf(cmin[3], fmaf(-2.f, acc[m][3][rr], nim));
                }
            #pragma unroll
            for (int n = 0; n < 4; ++n) {
                float c = cmin[n];
                c = fminf(c, __shfl_xor(c, 16, 64));
                c = fminf(c, __shfl_xor(c, 32, 64));
                if (ln < 16) cs[wv][nh * 64 + n * 16 + ln] = c;
            }
        } else {
            #pragma unroll
            for (int m = 0; m < 4; ++m)
                #pragma unroll
                for (int rr = 0; rr < 4; ++rr) {
                    int ir = wv * 64 + m * 16 + rg + rr;       // local i-row
                    int jc = nh * 64 + lr;                      // local j-col
                    float t0 = (ir == jc)      ? 1e30f
                               : fmaf(-2.f, acc[m][0][rr], nj[0]);
                    float t1 = (ir == jc + 16) ? 1e30f
                               : fmaf(-2.f, acc[m][1][rr], nj[1]);
                    float t2 = (ir == jc + 32) ? 1e30f
                               : fmaf(-2.f, acc[m][2][rr], nj[2]);
                    float t3 = (ir == jc + 48) ? 1e30f
                               : fmaf(-2.f, acc[m][3][rr], nj[3]);
                    rmin[m * 4 + rr] = fminf(rmin[m * 4 + rr],
                                             fminf(fminf(t0, t1), fminf(t2, t3)));
                }
        }
    }

    // Row-side: min across the 16 column-lanes, then one atomic per row.
    #pragma unroll
    for (int o = 1; o < 16; o <<= 1)
        #pragma unroll
        for (int q = 0; q < 16; ++q)
            rmin[q] = fminf(rmin[q], __shfl_xor(rmin[q], o, 64));
    if (lr == 0) {
        #pragma unroll
        for (int m = 0; m < 4; ++m)
            #pragma unroll
            for (int rr = 0; rr < 4; ++rr) {
                int row = ibase + wv * 64 + m * 16 + rg + rr;
                atomicMin(pmk + b * N_ + row, minkey(rmin[m * 4 + rr]));
            }
    }

    // Col-side: cross-wave reduce in LDS, one atomic per column.
    if (!diag) {
        __syncthreads();
        float c = cs[0][tid];
        #pragma unroll
        for (int w = 1; w < 4; ++w) c = fminf(c, cs[w][tid]);
        atomicMin(pmk + b * N_ + jbase + tid, minkey(c));
    }

    // Done-counter: the 576th-arriving WG finalizes.
    if (tid == 0) {
        __threadfence();
        unsigned old = atomicAdd(fincnt, 1u);
        lastflag = (old == 575u);
    }
    __syncthreads();
    if (lastflag) {
        const int M = B_ * N_;
        double s1 = 0.0, s2 = 0.0;
        for (int i = tid; i < M; i += 256) {
            unsigned key = __hip_atomic_load(&pmk[i], __ATOMIC_RELAXED,
                                             __HIP_MEMORY_SCOPE_AGENT);
            unsigned u = (key & 0x80000000u) ? (key ^ 0x80000000u) : ~key;
            float d2 = sqn[i] + __uint_as_float(u);   // sqn: prior kernel, coherent
            float x32 = sqrtf(fmaxf(d2, 0.f));
            double x = (double)x32;
            s1 += x; s2 += x * x;
        }
        #pragma unroll
        for (int o = 32; o; o >>= 1) {
            s1 += __shfl_down(s1, o, 64);
            s2 += __shfl_down(s2, o, 64);
        }
        if (ln == 0) { fa1[wv] = s1; fa2[wv] = s2; }
        __syncthreads();
        if (tid == 0) {
            double T1 = 0.0, T2 = 0.0;
            #pragma unroll
            for (int w = 0; w < 4; ++w) { T1 += fa1[w]; T2 += fa2[w]; }
            double mean = T1 / M;
            double var  = (T2 - T1 * T1 / M) / (M - 1);
            double stdv = var > 0.0 ? sqrt(var) : 0.0;
            double cv   = (mean > 1e-8) ? stdv / fmax(mean, 1e-8) : 0.0;
            out[0] = (float)mean;
            out[1] = (float)stdv;
            out[2] = (float)cv;
        }
    }
}

extern "C" void kernel_launch(void* const* d_in, const int* in_sizes, int n_in,
                              void* d_out, int out_size, void* d_ws, size_t ws_size,
                              hipStream_t stream) {
    const float* X = (const float*)d_in[0];
    const size_t XS_BYTES = (size_t)B_ * N_ * D_ * 2;        // 8 MB
    char* ws = (char*)d_ws;
    unsigned short* Xs     = (unsigned short*)ws;
    float*          sqn    = (float*)(ws + XS_BYTES);
    unsigned*       pmk    = (unsigned*)(ws + XS_BYTES + (size_t)B_ * N_ * 4);
    unsigned*       fincnt = (unsigned*)(ws + XS_BYTES + (size_t)B_ * N_ * 8);
    float*          out    = (float*)d_out;

    prep_kernel<<<B_ * N_ / 4, 256, 0, stream>>>(X, Xs, sqn, pmk, fincnt);
    nnd_kernel<<<16 * 36, 256, 0, stream>>>(Xs, sqn, pmk, fincnt, out);
}

// Round 5
// 36.784 us; speedup vs baseline: 2.1980x; 2.1980x over previous
//
#include <hip/hip_runtime.h>
#include <math.h>

// Problem constants (reference is fixed-shape).
#define B_ 16
#define N_ 2048
#define D_ 128

typedef __attribute__((ext_vector_type(8))) short bf16x8;   // 8 bf16 = 4 VGPRs
typedef __attribute__((ext_vector_type(4))) float f32x4;

__device__ __forceinline__ unsigned short f2bf(float f) {
    unsigned u = __float_as_uint(f);
    u += 0x7FFFu + ((u >> 16) & 1u);
    return (unsigned short)(u >> 16);
}

__device__ __forceinline__ unsigned minkey(float f) {
    // order-preserving uint encoding of float (for atomicMin): exact, assoc.
    unsigned u = __float_as_uint(f);
    return u ^ ((unsigned)((int)u >> 31) | 0x80000000u);
}

// ---------------------------------------------------------------------------
// K1: fp32 -> bf16 (pre-swizzled) + fp32 squared norms + per-call re-init of
// pmk keys and the finalize counter (harness does not re-poison between
// replays; ALL workspace state must be rebuilt every call).
// Swizzle: element d of row r stored at d ^ ((r&7)<<3): a linear global->LDS
// copy then gives conflict-free ds_read_b128 when read with the same XOR.
// ---------------------------------------------------------------------------
__global__ __launch_bounds__(256) void prep_kernel(
        const float* __restrict__ X, unsigned short* __restrict__ Xs,
        float* __restrict__ sqn, unsigned* __restrict__ pmk,
        unsigned* __restrict__ fincnt) {
    int row = blockIdx.x * 4 + (threadIdx.x >> 6);
    int ln  = threadIdx.x & 63;
    const float* src = X + (size_t)row * D_;
    float2 v = *(const float2*)(src + ln * 2);
    unsigned short h0 = f2bf(v.x), h1 = f2bf(v.y);
    float f0 = __uint_as_float((unsigned)h0 << 16);
    float f1 = __uint_as_float((unsigned)h1 << 16);
    float s = f0 * f0 + f1 * f1;
    #pragma unroll
    for (int o = 32; o; o >>= 1) s += __shfl_xor(s, o, 64);
    int dsw = (ln * 2) ^ ((row & 7) << 3);
    *(unsigned*)(Xs + (size_t)row * D_ + dsw) =
        (unsigned)h0 | ((unsigned)h1 << 16);
    if (ln == 0) { sqn[row] = s; pmk[row] = 0xFFFFFFFFu; }
    if (blockIdx.x == 0 && threadIdx.x == 0) *fincnt = 0u;
}

// ---------------------------------------------------------------------------
// K2: fused Gram + row-min, pipelined.  512 WGs = 16 batches x 8 i-tiles
// (256 rows) x 4 j-quarters (512 cols).  WG = 256 thr / 4 waves; wave owns
// 64 i-rows with A-fragments in registers for the whole sweep.  The 4 j-tiles
// (128 cols each) are double-buffered in LDS (2 x 32 KB) via linear
// global_load_lds of the pre-swizzled layout: stage t+1 overlaps compute t
// (m97 pattern), one barrier per step.  NO fences, NO done-counter here —
// device-scope fences inside the hot kernel trigger per-XCD L2
// writeback/invalidate storms (round-4 lesson: 82 us, MfmaUtil 4%).
// Row-mins merge via uint-keyed atomicMin (exact float min, associative ->
// order-independent -> graph-deterministic).
// ---------------------------------------------------------------------------
__device__ __forceinline__ void stage_tile(const unsigned short* gsrc,
                                           unsigned short* lds, int wv, int ln) {
    // 32 KB tile, 4 waves: each wave copies 8 KB = 8 x (64 lanes x 16 B).
    const char* g = (const char*)gsrc + wv * 8192 + ln * 16;
    char*       l = (char*)lds + wv * 8192;          // wave-uniform LDS base
    #pragma unroll
    for (int i = 0; i < 8; ++i)
        __builtin_amdgcn_global_load_lds(
            (const __attribute__((address_space(1))) unsigned int*)(g + i * 1024),
            (__attribute__((address_space(3))) unsigned int*)(l + i * 1024),
            16, 0, 0);
}

__global__ __launch_bounds__(256, 2) void nnd_kernel(
        const unsigned short* __restrict__ Xs, const float* __restrict__ sqn,
        unsigned* __restrict__ pmk) {
    __shared__ unsigned short Xj[2][128 * D_];   // 2 x 32 KB -> 2 WGs/CU

    // XCD-chunked remap (512 = 8 x 64, bijective): 64 consecutive ids per
    // XCD -> 2 batches (1 MB of Xs) per XCD L2.
    int wg  = (int)blockIdx.x;
    int id  = (wg & 7) * 64 + (wg >> 3);
    int b   = id >> 5;           // 32 ids per batch
    int sub = id & 31;
    int it  = sub >> 2;          // 256-row i-tile (8 per batch)
    int jh  = sub & 3;           // 512-col j-quarter (4 tiles of 128)

    int tid = threadIdx.x, wv = tid >> 6, ln = tid & 63;
    int lr = ln & 15;                 // fragment row/col lane index
    int kg = (ln >> 4) * 8;           // A/B fragment k-group offset
    int rg = (ln >> 4) * 4;           // C/D fragment row-group offset

    const unsigned short* Xb  = Xs  + (size_t)b * N_ * D_;
    const float*          sqb = sqn + b * N_;
    int ibase = it * 256 + wv * 64;   // this wave's first i-row

    // A fragments: 64 rows x K=128, registers for the whole sweep.
    bf16x8 Af[4][4];
    #pragma unroll
    for (int m = 0; m < 4; ++m) {
        int r  = ibase + m * 16 + lr;
        const unsigned short* rp = Xb + (size_t)r * D_;
        int sw = (r & 7) << 3;
        #pragma unroll
        for (int ks = 0; ks < 4; ++ks)
            Af[m][ks] = *(const bf16x8*)(rp + ((ks * 32 + kg) ^ sw));
    }

    float rmin[16];
    #pragma unroll
    for (int q = 0; q < 16; ++q) rmin[q] = 1e30f;
    const f32x4 zero4 = {0.f, 0.f, 0.f, 0.f};

    stage_tile(Xb + (size_t)(jh * 4) * 128 * D_, Xj[0], wv, ln);
    __syncthreads();

    for (int t = 0; t < 4; ++t) {
        int jt = jh * 4 + t, cur = t & 1;
        if (t < 3)
            stage_tile(Xb + (size_t)(jt + 1) * 128 * D_, Xj[cur ^ 1], wv, ln);

        const unsigned short* L = &Xj[cur][0];
        bool dtile = (jt >> 1) == it >> 0 && false;  // placeholder, set below
        dtile = ((jt * 128) >> 8) == it;             // j-tile inside i-256-range

        #pragma unroll
        for (int half = 0; half < 2; ++half) {       // 64-col halves
            float nj[4];
            #pragma unroll
            for (int n = 0; n < 4; ++n)
                nj[n] = sqb[jt * 128 + half * 64 + n * 16 + lr];

            f32x4 acc[4][4];
            #pragma unroll
            for (int ks = 0; ks < 4; ++ks) {
                bf16x8 Bf[4];
                #pragma unroll
                for (int n = 0; n < 4; ++n) {
                    int c = half * 64 + n * 16 + lr;
                    Bf[n] = *(const bf16x8*)(&L[c * D_ +
                                             ((ks * 32 + kg) ^ ((c & 7) << 3))]);
                }
                #pragma unroll
                for (int m = 0; m < 4; ++m)
                    #pragma unroll
                    for (int n = 0; n < 4; ++n)
                        acc[m][n] = __builtin_amdgcn_mfma_f32_16x16x32_bf16(
                            Af[m][ks], Bf[n], ks ? acc[m][n] : zero4, 0, 0, 0);
            }

            // Fold min_j (n_j - 2 g).  C/D: col = lane&15, row = rg + reg.
            if (!dtile) {
                #pragma unroll
                for (int m = 0; m < 4; ++m)
                    #pragma unroll
                    for (int rr = 0; rr < 4; ++rr) {
                        float t0 = fmaf(-2.f, acc[m][0][rr], nj[0]);
                        float t1 = fmaf(-2.f, acc[m][1][rr], nj[1]);
                        float t2 = fmaf(-2.f, acc[m][2][rr], nj[2]);
                        float t3 = fmaf(-2.f, acc[m][3][rr], nj[3]);
                        rmin[m * 4 + rr] = fminf(rmin[m * 4 + rr],
                                          fminf(fminf(t0, t1), fminf(t2, t3)));
                    }
            } else {
                #pragma unroll
                for (int m = 0; m < 4; ++m)
                    #pragma unroll
                    for (int rr = 0; rr < 4; ++rr) {
                        int ir = ibase + m * 16 + rg + rr;       // global row
                        int jc = jt * 128 + half * 64 + lr;      // global col
                        float t0 = (ir == jc)      ? 1e30f
                                   : fmaf(-2.f, acc[m][0][rr], nj[0]);
                        float t1 = (ir == jc + 16) ? 1e30f
                                   : fmaf(-2.f, acc[m][1][rr], nj[1]);
                        float t2 = (ir == jc + 32) ? 1e30f
                                   : fmaf(-2.f, acc[m][2][rr], nj[2]);
                        float t3 = (ir == jc + 48) ? 1e30f
                                   : fmaf(-2.f, acc[m][3][rr], nj[3]);
                        rmin[m * 4 + rr] = fminf(rmin[m * 4 + rr],
                                          fminf(fminf(t0, t1), fminf(t2, t3)));
                    }
            }
        }
        __syncthreads();
    }

    // Min across the 16 column-lanes, then one atomicMin per row (no return,
    // fire-and-forget; no fence needed — finalize runs after kernel boundary).
    #pragma unroll
    for (int o = 1; o < 16; o <<= 1)
        #pragma unroll
        for (int q = 0; q < 16; ++q)
            rmin[q] = fminf(rmin[q], __shfl_xor(rmin[q], o, 64));
    if (lr == 0) {
        #pragma unroll
        for (int m = 0; m < 4; ++m)
            #pragma unroll
            for (int rr = 0; rr < 4; ++rr) {
                int row = ibase + m * 16 + rg + rr;
                atomicMin(pmk + b * N_ + row, minkey(rmin[m * 4 + rr]));
            }
    }
}

// ---------------------------------------------------------------------------
// K3: decode keys -> nnd; mean / unbiased std / CV.  64 WGs write fixed f64
// partial slots; the last-arriving WG (device counter) sums the slots with
// agent-scope atomic loads.  Fences live ONLY here (tiny kernel, after the
// nnd kernel boundary).
// ---------------------------------------------------------------------------
__global__ __launch_bounds__(512) void finalize_kernel(
        const unsigned* __restrict__ pmk, const float* __restrict__ sqn,
        double* __restrict__ slots, unsigned* __restrict__ fincnt,
        float* __restrict__ out) {
    const int M = B_ * N_;
    int r = blockIdx.x * 512 + (int)threadIdx.x;
    unsigned key = pmk[r];
    unsigned u   = (key & 0x80000000u) ? (key ^ 0x80000000u) : ~key;
    float d2 = sqn[r] + __uint_as_float(u);
    float x32 = sqrtf(fmaxf(d2, 0.f));       // reference uses f32 sqrt too
    double x = (double)x32;
    double s1 = x, s2 = x * x;
    #pragma unroll
    for (int o = 32; o; o >>= 1) {
        s1 += __shfl_down(s1, o, 64);
        s2 += __shfl_down(s2, o, 64);
    }
    __shared__ double a1[8], a2[8];
    int wv = threadIdx.x >> 6, ln = threadIdx.x & 63;
    if (ln == 0) { a1[wv] = s1; a2[wv] = s2; }
    __syncthreads();
    if (threadIdx.x == 0) {
        double S1 = 0.0, S2 = 0.0;
        #pragma unroll
        for (int w = 0; w < 8; ++w) { S1 += a1[w]; S2 += a2[w]; }
        slots[blockIdx.x * 2]     = S1;
        slots[blockIdx.x * 2 + 1] = S2;
        __threadfence();
        unsigned old = atomicAdd(fincnt, 1u);
        if (old == 63u) {
            double T1 = 0.0, T2 = 0.0;
            for (int w = 0; w < 64; ++w) {
                T1 += __hip_atomic_load(&slots[w * 2],     __ATOMIC_RELAXED,
                                        __HIP_MEMORY_SCOPE_AGENT);
                T2 += __hip_atomic_load(&slots[w * 2 + 1], __ATOMIC_RELAXED,
                                        __HIP_MEMORY_SCOPE_AGENT);
            }
            double mean = T1 / M;
            double var  = (T2 - T1 * T1 / M) / (M - 1);
            double stdv = var > 0.0 ? sqrt(var) : 0.0;
            double cv   = (mean > 1e-8) ? stdv / fmax(mean, 1e-8) : 0.0;
            out[0] = (float)mean;
            out[1] = (float)stdv;
            out[2] = (float)cv;
        }
    }
}

extern "C" void kernel_launch(void* const* d_in, const int* in_sizes, int n_in,
                              void* d_out, int out_size, void* d_ws, size_t ws_size,
                              hipStream_t stream) {
    const float* X = (const float*)d_in[0];
    const size_t XS_BYTES = (size_t)B_ * N_ * D_ * 2;        // 8 MB
    char* ws = (char*)d_ws;
    unsigned short* Xs     = (unsigned short*)ws;
    float*          sqn    = (float*)(ws + XS_BYTES);
    unsigned*       pmk    = (unsigned*)(ws + XS_BYTES + (size_t)B_ * N_ * 4);
    double*         slots  = (double*)(ws + XS_BYTES + (size_t)B_ * N_ * 8);
    unsigned*       fincnt = (unsigned*)(ws + XS_BYTES + (size_t)B_ * N_ * 8 + 1024);
    float*          out    = (float*)d_out;

    prep_kernel<<<B_ * N_ / 4, 256, 0, stream>>>(X, Xs, sqn, pmk, fincnt);
    nnd_kernel<<<512, 256, 0, stream>>>(Xs, sqn, pmk);
    finalize_kernel<<<B_ * N_ / 512, 512, 0, stream>>>(pmk, sqn, slots, fincnt, out);
}

// Round 7
// 35.622 us; speedup vs baseline: 2.2697x; 1.0326x over previous
//
#include <hip/hip_runtime.h>
#include <math.h>

// Problem constants (reference is fixed-shape).
#define B_ 16
#define N_ 2048
#define D_ 128

typedef __attribute__((ext_vector_type(8))) short bf16x8;   // 8 bf16 = 4 VGPRs
typedef __attribute__((ext_vector_type(4))) float f32x4;

__device__ __forceinline__ unsigned short f2bf(float f) {
    unsigned u = __float_as_uint(f);
    u += 0x7FFFu + ((u >> 16) & 1u);
    return (unsigned short)(u >> 16);
}

__device__ __forceinline__ unsigned minkey(float f) {
    // order-preserving uint encoding of float (for atomicMin): exact, assoc.
    unsigned u = __float_as_uint(f);
    return u ^ ((unsigned)((int)u >> 31) | 0x80000000u);
}

// Fragment-order element offset within a 128x128 bf16 tile.
// Chunks of 8 k-elems laid out so that one MFMA B-fragment read instruction
// (fixed ks/half/n; lane ln = kg-quarter*16 + lr) covers 1024 CONTIGUOUS
// bytes: chunk index = (ks*8 + half*4 + n)*64 + ln.  This makes every
// ds_read_b128 bank-conflict-free by construction (round-5 lesson: the old
// (c&7)<<3 XOR left kg-quarters colliding -> 8-way conflict, +8cy/read,
// confirmed by R4's SQ_LDS_BANK_CONFLICT/read = 8.0).
__device__ __forceinline__ int frag_off(int c, int k) {
    return ((((k >> 5) * 8 + (c >> 6) * 4 + ((c >> 4) & 3)) * 64
             + ((k >> 3) & 3) * 16 + (c & 15)) * 8) + (k & 7);
}

// ---------------------------------------------------------------------------
// K1: fp32 -> bf16 in fragment-ordered tiles + fp32 squared norms + per-call
// re-init of pmk keys and the finalize counter (harness does not re-poison
// between replays; ALL workspace state must be rebuilt every call).
// ---------------------------------------------------------------------------
__global__ __launch_bounds__(256) void prep_kernel(
        const float* __restrict__ X, unsigned short* __restrict__ Xs,
        float* __restrict__ sqn, unsigned* __restrict__ pmk,
        unsigned* __restrict__ fincnt) {
    int row = blockIdx.x * 4 + (threadIdx.x >> 6);
    int ln  = threadIdx.x & 63;
    const float* src = X + (size_t)row * D_;
    float2 v = *(const float2*)(src + ln * 2);
    unsigned short h0 = f2bf(v.x), h1 = f2bf(v.y);
    float f0 = __uint_as_float((unsigned)h0 << 16);
    float f1 = __uint_as_float((unsigned)h1 << 16);
    float s = f0 * f0 + f1 * f1;
    #pragma unroll
    for (int o = 32; o; o >>= 1) s += __shfl_xor(s, o, 64);
    int c   = row & 127;                       // row within its 128-row tile
    int off = frag_off(c, ln * 2);             // k&7 even -> pair stays intact
    *(unsigned*)(Xs + (((size_t)(row >> 7)) << 14) + off) =
        (unsigned)h0 | ((unsigned)h1 << 16);
    if (ln == 0) { sqn[row] = s; pmk[row] = 0xFFFFFFFFu; }
    if (blockIdx.x == 0 && threadIdx.x == 0) *fincnt = 0u;
}

// ---------------------------------------------------------------------------
// K2: fused Gram + row-min, pipelined.  512 WGs = 16 batches x 8 i-tiles
// (256 rows) x 4 j-quarters.  WG = 256 thr / 4 waves; wave owns 64 i-rows
// with A-fragments in registers.  j-tiles (128 rows, fragment-ordered 32 KB)
// double-buffered in LDS via linear global_load_lds; B-fragment ds_read_b128
// are fully linear per instruction (conflict-free, imm-offset addressing).
// NO device-scope fences here (round-4 lesson: fence storm = L2 invalidate
// storm, 82 us).  Row-mins merge via uint-keyed atomicMin (exact float min,
// associative -> order-independent -> graph-deterministic).
// ---------------------------------------------------------------------------
__device__ __forceinline__ void stage_tile(const unsigned short* gsrc,
                                           unsigned short* lds, int wv, int ln) {
    // 32 KB fragment-ordered tile, 4 waves: each wave copies 8 KB linearly.
    const char* g = (const char*)gsrc + wv * 8192 + ln * 16;
    char*       l = (char*)lds + wv * 8192;          // wave-uniform LDS base
    #pragma unroll
    for (int i = 0; i < 8; ++i)
        __builtin_amdgcn_global_load_lds(
            (const __attribute__((address_space(1))) unsigned int*)(g + i * 1024),
            (__attribute__((address_space(3))) unsigned int*)(l + i * 1024),
            16, 0, 0);
}

__global__ __launch_bounds__(256, 2) void nnd_kernel(
        const unsigned short* __restrict__ Xs, const float* __restrict__ sqn,
        unsigned* __restrict__ pmk) {
    __shared__ unsigned short Xj[2][128 * D_];   // 2 x 32 KB -> 2 WGs/CU

    // XCD-chunked remap (512 = 8 x 64, bijective): 64 consecutive ids per
    // XCD -> 2 batches (1 MB of Xs) per XCD L2.
    int wg  = (int)blockIdx.x;
    int id  = (wg & 7) * 64 + (wg >> 3);
    int b   = id >> 5;           // 32 ids per batch
    int sub = id & 31;
    int it  = sub >> 2;          // 256-row i-tile (8 per batch)
    int jh  = sub & 3;           // 512-col j-quarter (4 tiles of 128)

    int tid = threadIdx.x, wv = tid >> 6, ln = tid & 63;
    int lr = ln & 15;                 // fragment row/col lane index
    int kg = (ln >> 4) * 8;           // A/B fragment k-group offset
    int rg = (ln >> 4) * 4;           // C/D fragment row-group offset

    const unsigned short* Xb  = Xs  + (size_t)b * N_ * D_;
    const float*          sqb = sqn + b * N_;
    int ibase = it * 256 + wv * 64;   // this wave's first i-row

    // A fragments: 64 rows x K=128 from the fragment-ordered global layout.
    bf16x8 Af[4][4];
    #pragma unroll
    for (int m = 0; m < 4; ++m) {
        int r = ibase + m * 16 + lr;
        const unsigned short* tp = Xb + (((size_t)(r >> 7)) << 14);
        int c = r & 127;
        #pragma unroll
        for (int ks = 0; ks < 4; ++ks)
            Af[m][ks] = *(const bf16x8*)(tp + frag_off(c, ks * 32 + kg));
    }

    float rmin[16];
    #pragma unroll
    for (int q = 0; q < 16; ++q) rmin[q] = 1e30f;
    const f32x4 zero4 = {0.f, 0.f, 0.f, 0.f};

    stage_tile(Xb + ((size_t)(jh * 4) << 14), Xj[0], wv, ln);
    __syncthreads();

    for (int t = 0; t < 4; ++t) {
        int jt = jh * 4 + t, cur = t & 1;
        if (t < 3)
            stage_tile(Xb + ((size_t)(jt + 1) << 14), Xj[cur ^ 1], wv, ln);

        const unsigned short* L = &Xj[cur][0];
        bool dtile = (jt >> 1) == it;      // j-tile inside this i-256-range

        #pragma unroll
        for (int half = 0; half < 2; ++half) {       // 64-col halves
            float nj[4];
            #pragma unroll
            for (int n = 0; n < 4; ++n)
                nj[n] = sqb[jt * 128 + half * 64 + n * 16 + lr];

            f32x4 acc[4][4];
            #pragma unroll
            for (int ks = 0; ks < 4; ++ks) {
                bf16x8 Bf[4];
                #pragma unroll
                for (int n = 0; n < 4; ++n)
                    Bf[n] = *(const bf16x8*)(
                        &L[((ks * 8 + half * 4 + n) * 64 + ln) * 8]);
                #pragma unroll
                for (int m = 0; m < 4; ++m)
                    #pragma unroll
                    for (int n = 0; n < 4; ++n)
                        acc[m][n] = __builtin_amdgcn_mfma_f32_16x16x32_bf16(
                            Af[m][ks], Bf[n], ks ? acc[m][n] : zero4, 0, 0, 0);
            }

            // Fold min_j (n_j - 2 g).  C/D: col = lane&15, row = rg + reg.
            if (!dtile) {
                #pragma unroll
                for (int m = 0; m < 4; ++m)
                    #pragma unroll
                    for (int rr = 0; rr < 4; ++rr) {
                        float t0 = fmaf(-2.f, acc[m][0][rr], nj[0]);
                        float t1 = fmaf(-2.f, acc[m][1][rr], nj[1]);
                        float t2 = fmaf(-2.f, acc[m][2][rr], nj[2]);
                        float t3 = fmaf(-2.f, acc[m][3][rr], nj[3]);
                        rmin[m * 4 + rr] = fminf(rmin[m * 4 + rr],
                                          fminf(fminf(t0, t1), fminf(t2, t3)));
                    }
            } else {
                #pragma unroll
                for (int m = 0; m < 4; ++m)
                    #pragma unroll
                    for (int rr = 0; rr < 4; ++rr) {
                        int ir = ibase + m * 16 + rg + rr;       // global row
                        int jc = jt * 128 + half * 64 + lr;      // global col
                        float t0 = (ir == jc)      ? 1e30f
                                   : fmaf(-2.f, acc[m][0][rr], nj[0]);
                        float t1 = (ir == jc + 16) ? 1e30f
                                   : fmaf(-2.f, acc[m][1][rr], nj[1]);
                        float t2 = (ir == jc + 32) ? 1e30f
                                   : fmaf(-2.f, acc[m][2][rr], nj[2]);
                        float t3 = (ir == jc + 48) ? 1e30f
                                   : fmaf(-2.f, acc[m][3][rr], nj[3]);
                        rmin[m * 4 + rr] = fminf(rmin[m * 4 + rr],
                                          fminf(fminf(t0, t1), fminf(t2, t3)));
                    }
            }
        }
        __syncthreads();
    }

    // Min across the 16 column-lanes, then one atomicMin per row.
    #pragma unroll
    for (int o = 1; o < 16; o <<= 1)
        #pragma unroll
        for (int q = 0; q < 16; ++q)
            rmin[q] = fminf(rmin[q], __shfl_xor(rmin[q], o, 64));
    if (lr == 0) {
        #pragma unroll
        for (int m = 0; m < 4; ++m)
            #pragma unroll
            for (int rr = 0; rr < 4; ++rr) {
                int row = ibase + m * 16 + rg + rr;
                atomicMin(pmk + b * N_ + row, minkey(rmin[m * 4 + rr]));
            }
    }
}

// ---------------------------------------------------------------------------
// K3: decode keys -> nnd; mean / unbiased std / CV.  64 WGs write fixed f64
// partial slots; the last-arriving WG (device counter) sums the slots with
// agent-scope atomic loads.  Fences live ONLY here (tiny tail kernel).
// ---------------------------------------------------------------------------
__global__ __launch_bounds__(512) void finalize_kernel(
        const unsigned* __restrict__ pmk, const float* __restrict__ sqn,
        double* __restrict__ slots, unsigned* __restrict__ fincnt,
        float* __restrict__ out) {
    const int M = B_ * N_;
    int r = blockIdx.x * 512 + (int)threadIdx.x;
    unsigned key = pmk[r];
    unsigned u   = (key & 0x80000000u) ? (key ^ 0x80000000u) : ~key;
    float d2 = sqn[r] + __uint_as_float(u);
    float x32 = sqrtf(fmaxf(d2, 0.f));       // reference uses f32 sqrt too
    double x = (double)x32;
    double s1 = x, s2 = x * x;
    #pragma unroll
    for (int o = 32; o; o >>= 1) {
        s1 += __shfl_down(s1, o, 64);
        s2 += __shfl_down(s2, o, 64);
    }
    __shared__ double a1[8], a2[8];
    int wv = threadIdx.x >> 6, ln = threadIdx.x & 63;
    if (ln == 0) { a1[wv] = s1; a2[wv] = s2; }
    __syncthreads();
    if (threadIdx.x == 0) {
        double S1 = 0.0, S2 = 0.0;
        #pragma unroll
        for (int w = 0; w < 8; ++w) { S1 += a1[w]; S2 += a2[w]; }
        slots[blockIdx.x * 2]     = S1;
        slots[blockIdx.x * 2 + 1] = S2;
        __threadfence();
        unsigned old = atomicAdd(fincnt, 1u);
        if (old == 63u) {
            double T1 = 0.0, T2 = 0.0;
            for (int w = 0; w < 64; ++w) {
                T1 += __hip_atomic_load(&slots[w * 2],     __ATOMIC_RELAXED,
                                        __HIP_MEMORY_SCOPE_AGENT);
                T2 += __hip_atomic_load(&slots[w * 2 + 1], __ATOMIC_RELAXED,
                                        __HIP_MEMORY_SCOPE_AGENT);
            }
            double mean = T1 / M;
            double var  = (T2 - T1 * T1 / M) / (M - 1);
            double stdv = var > 0.0 ? sqrt(var) : 0.0;
            double cv   = (mean > 1e-8) ? stdv / fmax(mean, 1e-8) : 0.0;
            out[0] = (float)mean;
            out[1] = (float)stdv;
            out[2] = (float)cv;
        }
    }
}

extern "C" void kernel_launch(void* const* d_in, const int* in_sizes, int n_in,
                              void* d_out, int out_size, void* d_ws, size_t ws_size,
                              hipStream_t stream) {
    const float* X = (const float*)d_in[0];
    const size_t XS_BYTES = (size_t)B_ * N_ * D_ * 2;        // 8 MB
    char* ws = (char*)d_ws;
    unsigned short* Xs     = (unsigned short*)ws;
    float*          sqn    = (float*)(ws + XS_BYTES);
    unsigned*       pmk    = (unsigned*)(ws + XS_BYTES + (size_t)B_ * N_ * 4);
    double*         slots  = (double*)(ws + XS_BYTES + (size_t)B_ * N_ * 8);
    unsigned*       fincnt = (unsigned*)(ws + XS_BYTES + (size_t)B_ * N_ * 8 + 1024);
    float*          out    = (float*)d_out;

    prep_kernel<<<B_ * N_ / 4, 256, 0, stream>>>(X, Xs, sqn, pmk, fincnt);
    nnd_kernel<<<512, 256, 0, stream>>>(Xs, sqn, pmk);
    finalize_kernel<<<B_ * N_ / 512, 512, 0, stream>>>(pmk, sqn, slots, fincnt, out);
}